// Round 1
// baseline (5242.918 us; speedup 1.0000x reference)
//
#include <hip/hip_runtime.h>
#include <math.h>

#define D_MODEL 1024
#define D_INNER 2048
#define D_STATE 16
#define D_CONV  4
#define DT_RANK 64
#define NB      2
#define LSEQ    1024
#define NROWS   (NB * LSEQ)   // 2048
#define LN_EPS  1e-5f
#define N_LAYER 4

// ---------------------------------------------------------------------------
// Fused residual-add + LayerNorm. One block per row (1024 cols, 256 thr x f4).
// first==1: residual = add ; else residual += add. Then out = LN(residual).
// ---------------------------------------------------------------------------
__device__ inline float wave_sum(float s) {
    #pragma unroll
    for (int m = 1; m < 64; m <<= 1) s += __shfl_xor(s, m, 64);
    return s;
}

__global__ __launch_bounds__(256)
void add_ln_kernel(const float* __restrict__ add, float* __restrict__ residual,
                   const float* __restrict__ w, const float* __restrict__ b,
                   float* __restrict__ out, int first)
{
    int row = blockIdx.x;
    int tid = threadIdx.x;
    size_t base = (size_t)row * D_MODEL + tid * 4;

    float4 v = *(const float4*)(add + base);
    if (!first) {
        float4 r = *(const float4*)(residual + base);
        v.x += r.x; v.y += r.y; v.z += r.z; v.w += r.w;
    }
    *(float4*)(residual + base) = v;

    __shared__ float red[8];
    float s = v.x + v.y + v.z + v.w;
    s = wave_sum(s);
    if ((tid & 63) == 0) red[tid >> 6] = s;
    __syncthreads();
    float mu = (red[0] + red[1] + red[2] + red[3]) * (1.0f / D_MODEL);

    float dx = v.x - mu, dy = v.y - mu, dz = v.z - mu, dw2 = v.w - mu;
    float s2 = dx*dx + dy*dy + dz*dz + dw2*dw2;
    s2 = wave_sum(s2);
    if ((tid & 63) == 0) red[4 + (tid >> 6)] = s2;
    __syncthreads();
    float var = (red[4] + red[5] + red[6] + red[7]) * (1.0f / D_MODEL);
    float rs = rsqrtf(var + LN_EPS);

    float4 wv = *(const float4*)(w + tid * 4);
    float4 bv = *(const float4*)(b + tid * 4);
    float4 o;
    o.x = dx  * rs * wv.x + bv.x;
    o.y = dy  * rs * wv.y + bv.y;
    o.z = dz  * rs * wv.z + bv.z;
    o.w = dw2 * rs * wv.w + bv.w;
    *(float4*)(out + base) = o;
}

// ---------------------------------------------------------------------------
// NT GEMM: C[M,N] = A[M,K] * B[N,K]^T.  64x64 tile, 4x4 per thread, KT=16.
// mode 0: plain store; mode 1: softplus(acc + bias[n])  (dt_proj epilogue)
// Requires K % 16 == 0, M % 64 == 0; N arbitrary (guarded).
// ---------------------------------------------------------------------------
#define TILE 64
#define KT   16

__global__ __launch_bounds__(256)
void gemm_nt(const float* __restrict__ A, const float* __restrict__ B,
             float* __restrict__ C, int M, int N, int K,
             int lda, int ldb, int ldc,
             const float* __restrict__ bias, int mode)
{
    __shared__ float As[KT][TILE + 4];
    __shared__ float Bs[KT][TILE + 4];

    int tid = threadIdx.x;
    int tx = tid & 15, ty = tid >> 4;
    int m0 = blockIdx.y * TILE;
    int n0 = blockIdx.x * TILE;

    int lr = tid >> 2;        // 0..63: tile row for loading
    int lk = (tid & 3) * 4;   // 0,4,8,12: k offset

    float acc[4][4] = {};

    for (int k0 = 0; k0 < K; k0 += KT) {
        {
            int m = m0 + lr;
            float4 v = *(const float4*)(A + (size_t)m * lda + k0 + lk);
            As[lk + 0][lr] = v.x; As[lk + 1][lr] = v.y;
            As[lk + 2][lr] = v.z; As[lk + 3][lr] = v.w;
        }
        {
            int n = n0 + lr;
            float4 v = make_float4(0.f, 0.f, 0.f, 0.f);
            if (n < N) v = *(const float4*)(B + (size_t)n * ldb + k0 + lk);
            Bs[lk + 0][lr] = v.x; Bs[lk + 1][lr] = v.y;
            Bs[lk + 2][lr] = v.z; Bs[lk + 3][lr] = v.w;
        }
        __syncthreads();
        #pragma unroll
        for (int kk = 0; kk < KT; ++kk) {
            float4 a4 = *(const float4*)&As[kk][ty * 4];
            float4 b4 = *(const float4*)&Bs[kk][tx * 4];
            float av[4] = {a4.x, a4.y, a4.z, a4.w};
            float bv[4] = {b4.x, b4.y, b4.z, b4.w};
            #pragma unroll
            for (int i = 0; i < 4; ++i)
                #pragma unroll
                for (int j = 0; j < 4; ++j)
                    acc[i][j] += av[i] * bv[j];
        }
        __syncthreads();
    }

    #pragma unroll
    for (int i = 0; i < 4; ++i) {
        int m = m0 + ty * 4 + i;
        #pragma unroll
        for (int j = 0; j < 4; ++j) {
            int n = n0 + tx * 4 + j;
            if (n >= N) continue;
            float v = acc[i][j];
            if (mode == 1) {
                v += bias[n];
                v = (v > 20.f) ? v : log1pf(__expf(v));  // softplus
            }
            C[(size_t)m * ldc + n] = v;
        }
    }
}

// ---------------------------------------------------------------------------
// Depthwise causal conv (width 4) + bias + SiLU. x = xz[..., :D_INNER].
// ---------------------------------------------------------------------------
__global__ __launch_bounds__(256)
void conv_silu_kernel(const float* __restrict__ xz, const float* __restrict__ cw,
                      const float* __restrict__ cb, float* __restrict__ xc)
{
    int idx = blockIdx.x * 256 + threadIdx.x;       // over NB*LSEQ*D_INNER = 4M
    int d  = idx & (D_INNER - 1);
    int t  = (idx >> 11) & (LSEQ - 1);
    int bb = idx >> 21;

    const float* xcol = xz + (size_t)bb * LSEQ * 2 * D_INNER + d;
    float acc = cb[d];
    #pragma unroll
    for (int k = 0; k < D_CONV; ++k) {
        int tt = t + k - (D_CONV - 1);
        if (tt >= 0) acc += xcol[(size_t)tt * 2 * D_INNER] * cw[d * D_CONV + k];
    }
    acc = acc / (1.f + __expf(-acc));  // silu
    xc[idx] = acc;
}

// ---------------------------------------------------------------------------
// Selective scan. Block = 16 d-channels x 16 states. Grid = NB * D_INNER/16.
// Per t: h = h*exp(dt*A) + dt*x*B[s]; y = sum_s h*C[s]; epilogue fused:
// y = (y + x*D) * silu(z).
// ---------------------------------------------------------------------------
__global__ __launch_bounds__(256)
void scan_kernel(const float* __restrict__ dtb, const float* __restrict__ xc,
                 const float* __restrict__ dbl, const float* __restrict__ xz,
                 const float* __restrict__ Alog, const float* __restrict__ Dp,
                 float* __restrict__ y)
{
    int tid = threadIdx.x;
    int s  = tid & 15;
    int dl = tid >> 4;                 // 0..15
    int blk = blockIdx.x;              // 0..255
    int bb = blk >> 7;                 // batch
    int d  = (blk & 127) * 16 + dl;

    float A  = -__expf(Alog[d * D_STATE + s]);
    float Dd = Dp[d];
    float h = 0.f;
    size_t rowbase = (size_t)bb * LSEQ;

    for (int t = 0; t < LSEQ; ++t) {
        size_t r = rowbase + t;
        float dt = dtb[r * D_INNER + d];
        float xv = xc [r * D_INNER + d];
        float Bv = dbl[r * 96 + DT_RANK + s];
        float Cv = dbl[r * 96 + DT_RANK + D_STATE + s];

        h = h * __expf(dt * A) + (dt * xv) * Bv;
        float p = h * Cv;
        p += __shfl_xor(p, 1, 16);
        p += __shfl_xor(p, 2, 16);
        p += __shfl_xor(p, 4, 16);
        p += __shfl_xor(p, 8, 16);
        if (s == 0) {
            float z = xz[r * 2 * D_INNER + D_INNER + d];
            float yv = (p + xv * Dd) * (z / (1.f + __expf(-z)));
            y[r * D_INNER + d] = yv;
        }
    }
}

// ---------------------------------------------------------------------------
extern "C" void kernel_launch(void* const* d_in, const int* in_sizes, int n_in,
                              void* d_out, int out_size, void* d_ws, size_t ws_size,
                              hipStream_t stream)
{
    const float* h_in  = (const float*)d_in[0];
    const float* iw    = (const float*)d_in[1];   // (4, 4096, 1024)
    const float* cw    = (const float*)d_in[2];   // (4, 2048, 4)
    const float* cb    = (const float*)d_in[3];   // (4, 2048)
    const float* xw    = (const float*)d_in[4];   // (4, 96, 2048)
    const float* dw    = (const float*)d_in[5];   // (4, 2048, 64)
    const float* db    = (const float*)d_in[6];   // (4, 2048)
    const float* Alog  = (const float*)d_in[7];   // (4, 2048, 16)
    const float* Dp    = (const float*)d_in[8];   // (4, 2048)
    const float* ow    = (const float*)d_in[9];   // (4, 1024, 2048)
    const float* nw    = (const float*)d_in[10];  // (4, 1024)
    const float* nb    = (const float*)d_in[11];  // (4, 1024)
    const float* nfw   = (const float*)d_in[12];  // (1024,)
    const float* nfb   = (const float*)d_in[13];  // (1024,)

    float* ws = (float*)d_ws;
    float* residual = ws;                       // 2,097,152
    float* hs       = residual + 2097152;       // 2,097,152 (LN out; reused as mamba out)
    float* xz       = hs + 2097152;             // 8,388,608
    float* xc       = xz + 8388608;             // 4,194,304
    float* dtb      = xc + 4194304;             // 4,194,304
    float* dbl      = dtb + 4194304;            // 196,608
    float* y        = dbl + 196608;             // 4,194,304

    const float* cur_add = h_in;
    for (int i = 0; i < N_LAYER; ++i) {
        add_ln_kernel<<<NROWS, 256, 0, stream>>>(cur_add, residual,
                                                 nw + i * D_MODEL, nb + i * D_MODEL,
                                                 hs, i == 0);
        // in_proj: (2048 x 1024) * (4096 x 1024)^T -> (2048 x 4096)
        gemm_nt<<<dim3(2 * D_INNER / TILE, NROWS / TILE), 256, 0, stream>>>(
            hs, iw + (size_t)i * 2 * D_INNER * D_MODEL, xz,
            NROWS, 2 * D_INNER, D_MODEL, D_MODEL, D_MODEL, 2 * D_INNER, nullptr, 0);
        // conv + silu
        conv_silu_kernel<<<NB * LSEQ * D_INNER / 256, 256, 0, stream>>>(
            xz, cw + (size_t)i * D_INNER * D_CONV, cb + i * D_INNER, xc);
        // x_proj: (2048 x 2048) * (96 x 2048)^T -> (2048 x 96)
        gemm_nt<<<dim3(2, NROWS / TILE), 256, 0, stream>>>(
            xc, xw + (size_t)i * 96 * D_INNER, dbl,
            NROWS, 96, D_INNER, D_INNER, D_INNER, 96, nullptr, 0);
        // dt_proj + softplus: (2048 x 64 [lda=96]) * (2048 x 64)^T -> (2048 x 2048)
        gemm_nt<<<dim3(D_INNER / TILE, NROWS / TILE), 256, 0, stream>>>(
            dbl, dw + (size_t)i * D_INNER * DT_RANK, dtb,
            NROWS, D_INNER, DT_RANK, 96, DT_RANK, D_INNER, db + i * D_INNER, 1);
        // selective scan (+ D skip + silu(z) gate)
        scan_kernel<<<NB * D_INNER / 16, 256, 0, stream>>>(
            dtb, xc, dbl, xz, Alog + (size_t)i * D_INNER * D_STATE, Dp + i * D_INNER, y);
        // out_proj: (2048 x 2048) * (1024 x 2048)^T -> (2048 x 1024), into hs
        gemm_nt<<<dim3(D_MODEL / TILE, NROWS / TILE), 256, 0, stream>>>(
            y, ow + (size_t)i * D_MODEL * D_INNER, hs,
            NROWS, D_MODEL, D_INNER, D_INNER, D_INNER, D_MODEL, nullptr, 0);
        cur_add = hs;
    }
    add_ln_kernel<<<NROWS, 256, 0, stream>>>(hs, residual, nfw, nfb, (float*)d_out, 0);
}

// Round 2
// 3775.183 us; speedup vs baseline: 1.3888x; 1.3888x over previous
//
#include <hip/hip_runtime.h>
#include <math.h>

#define D_MODEL 1024
#define D_INNER 2048
#define D_STATE 16
#define D_CONV  4
#define DT_RANK 64
#define NB      2
#define LSEQ    1024
#define NROWS   (NB * LSEQ)   // 2048
#define LN_EPS  1e-5f
#define N_LAYER 4

// ---------------------------------------------------------------------------
// Fused residual-add + LayerNorm. One block per row (1024 cols, 256 thr x f4).
// first==1: residual = add ; else residual += add. Then out = LN(residual).
// ---------------------------------------------------------------------------
__device__ inline float wave_sum(float s) {
    #pragma unroll
    for (int m = 1; m < 64; m <<= 1) s += __shfl_xor(s, m, 64);
    return s;
}

__global__ __launch_bounds__(256)
void add_ln_kernel(const float* __restrict__ add, float* __restrict__ residual,
                   const float* __restrict__ w, const float* __restrict__ b,
                   float* __restrict__ out, int first)
{
    int row = blockIdx.x;
    int tid = threadIdx.x;
    size_t base = (size_t)row * D_MODEL + tid * 4;

    float4 v = *(const float4*)(add + base);
    if (!first) {
        float4 r = *(const float4*)(residual + base);
        v.x += r.x; v.y += r.y; v.z += r.z; v.w += r.w;
    }
    *(float4*)(residual + base) = v;

    __shared__ float red[8];
    float s = v.x + v.y + v.z + v.w;
    s = wave_sum(s);
    if ((tid & 63) == 0) red[tid >> 6] = s;
    __syncthreads();
    float mu = (red[0] + red[1] + red[2] + red[3]) * (1.0f / D_MODEL);

    float dx = v.x - mu, dy = v.y - mu, dz = v.z - mu, dw2 = v.w - mu;
    float s2 = dx*dx + dy*dy + dz*dz + dw2*dw2;
    s2 = wave_sum(s2);
    if ((tid & 63) == 0) red[4 + (tid >> 6)] = s2;
    __syncthreads();
    float var = (red[4] + red[5] + red[6] + red[7]) * (1.0f / D_MODEL);
    float rs = rsqrtf(var + LN_EPS);

    float4 wv = *(const float4*)(w + tid * 4);
    float4 bv = *(const float4*)(b + tid * 4);
    float4 o;
    o.x = dx  * rs * wv.x + bv.x;
    o.y = dy  * rs * wv.y + bv.y;
    o.z = dz  * rs * wv.z + bv.z;
    o.w = dw2 * rs * wv.w + bv.w;
    *(float4*)(out + base) = o;
}

// ---------------------------------------------------------------------------
// NT GEMM: C[M,N] = A[M,K] * B[N,K]^T.  64x64 tile, 4x4 per thread, KT=16.
// mode 0: plain store; mode 1: softplus(acc + bias[n])  (dt_proj epilogue)
// ---------------------------------------------------------------------------
#define TILE 64
#define KT   16

__global__ __launch_bounds__(256)
void gemm_nt(const float* __restrict__ A, const float* __restrict__ B,
             float* __restrict__ C, int M, int N, int K,
             int lda, int ldb, int ldc,
             const float* __restrict__ bias, int mode)
{
    __shared__ float As[KT][TILE + 4];
    __shared__ float Bs[KT][TILE + 4];

    int tid = threadIdx.x;
    int tx = tid & 15, ty = tid >> 4;
    int m0 = blockIdx.y * TILE;
    int n0 = blockIdx.x * TILE;

    int lr = tid >> 2;        // 0..63: tile row for loading
    int lk = (tid & 3) * 4;   // 0,4,8,12: k offset

    float acc[4][4] = {};

    for (int k0 = 0; k0 < K; k0 += KT) {
        {
            int m = m0 + lr;
            float4 v = *(const float4*)(A + (size_t)m * lda + k0 + lk);
            As[lk + 0][lr] = v.x; As[lk + 1][lr] = v.y;
            As[lk + 2][lr] = v.z; As[lk + 3][lr] = v.w;
        }
        {
            int n = n0 + lr;
            float4 v = make_float4(0.f, 0.f, 0.f, 0.f);
            if (n < N) v = *(const float4*)(B + (size_t)n * ldb + k0 + lk);
            Bs[lk + 0][lr] = v.x; Bs[lk + 1][lr] = v.y;
            Bs[lk + 2][lr] = v.z; Bs[lk + 3][lr] = v.w;
        }
        __syncthreads();
        #pragma unroll
        for (int kk = 0; kk < KT; ++kk) {
            float4 a4 = *(const float4*)&As[kk][ty * 4];
            float4 b4 = *(const float4*)&Bs[kk][tx * 4];
            float av[4] = {a4.x, a4.y, a4.z, a4.w};
            float bv[4] = {b4.x, b4.y, b4.z, b4.w};
            #pragma unroll
            for (int i = 0; i < 4; ++i)
                #pragma unroll
                for (int j = 0; j < 4; ++j)
                    acc[i][j] += av[i] * bv[j];
        }
        __syncthreads();
    }

    #pragma unroll
    for (int i = 0; i < 4; ++i) {
        int m = m0 + ty * 4 + i;
        #pragma unroll
        for (int j = 0; j < 4; ++j) {
            int n = n0 + tx * 4 + j;
            if (n >= N) continue;
            float v = acc[i][j];
            if (mode == 1) {
                v += bias[n];
                v = (v > 20.f) ? v : log1pf(__expf(v));  // softplus
            }
            C[(size_t)m * ldc + n] = v;
        }
    }
}

// ---------------------------------------------------------------------------
// Depthwise causal conv (width 4) + bias + SiLU. x = xz[..., :D_INNER].
// ---------------------------------------------------------------------------
__global__ __launch_bounds__(256)
void conv_silu_kernel(const float* __restrict__ xz, const float* __restrict__ cw,
                      const float* __restrict__ cb, float* __restrict__ xc)
{
    int idx = blockIdx.x * 256 + threadIdx.x;       // over NB*LSEQ*D_INNER = 4M
    int d  = idx & (D_INNER - 1);
    int t  = (idx >> 11) & (LSEQ - 1);
    int bb = idx >> 21;

    const float* xcol = xz + (size_t)bb * LSEQ * 2 * D_INNER + d;
    float acc = cb[d];
    #pragma unroll
    for (int k = 0; k < D_CONV; ++k) {
        int tt = t + k - (D_CONV - 1);
        if (tt >= 0) acc += xcol[(size_t)tt * 2 * D_INNER] * cw[d * D_CONV + k];
    }
    acc = acc / (1.f + __expf(-acc));  // silu
    xc[idx] = acc;
}

// ---------------------------------------------------------------------------
// Selective scan, v2: 4 states per lane, 4 lanes per d-channel.
// One wave (64 lanes) handles 16 d-channels; grid = NB * D_INNER/16 = 256
// single-wave blocks (one per CU). h[4] lives in registers; all t-dependent
// loads are software-pipelined one step ahead; only dependence across steps
// is h = h*exp(dt*A) + (dt*x)*B  (exp+fma, ~15 cy).
// Epilogue fused: y = (p + x*D) * silu(z).
// ---------------------------------------------------------------------------
__global__ __launch_bounds__(64)
void scan_kernel(const float* __restrict__ dtb, const float* __restrict__ xc,
                 const float* __restrict__ dbl, const float* __restrict__ xz,
                 const float* __restrict__ Alog, const float* __restrict__ Dp,
                 float* __restrict__ y)
{
    int lane = threadIdx.x;            // 0..63
    int q    = lane & 3;               // state quad: states q*4 .. q*4+3
    int dl   = lane >> 2;              // 0..15: d-channel within wave
    int blk  = blockIdx.x;             // 0..255
    int bb   = blk >> 7;               // batch
    int d    = (blk & 127) * 16 + dl;

    float A[4], h[4] = {0.f, 0.f, 0.f, 0.f};
    #pragma unroll
    for (int j = 0; j < 4; ++j)
        A[j] = -__expf(Alog[d * D_STATE + q * 4 + j]);
    float Dd = Dp[d];

    size_t rowbase = (size_t)bb * LSEQ;

    // prefetch t = 0
    size_t r0 = rowbase;
    float  dt = dtb[r0 * D_INNER + d];
    float  xv = xc [r0 * D_INNER + d];
    float4 Bv = *(const float4*)(dbl + r0 * 96 + DT_RANK + q * 4);
    float4 Cv = *(const float4*)(dbl + r0 * 96 + DT_RANK + D_STATE + q * 4);
    float  zv = xz [r0 * 2 * D_INNER + D_INNER + d];

    for (int t = 0; t < LSEQ; ++t) {
        // prefetch t+1 (wraps to row 0 on the last iter; values unused)
        size_t rn = rowbase + ((t + 1) & (LSEQ - 1));
        float  dt_n = dtb[rn * D_INNER + d];
        float  xv_n = xc [rn * D_INNER + d];
        float4 Bv_n = *(const float4*)(dbl + rn * 96 + DT_RANK + q * 4);
        float4 Cv_n = *(const float4*)(dbl + rn * 96 + DT_RANK + D_STATE + q * 4);
        float  zv_n = xz [rn * 2 * D_INNER + D_INNER + d];

        // compute step t
        float dtx = dt * xv;
        float Bb[4] = {Bv.x, Bv.y, Bv.z, Bv.w};
        float Cc[4] = {Cv.x, Cv.y, Cv.z, Cv.w};
        float p = 0.f;
        #pragma unroll
        for (int j = 0; j < 4; ++j) {
            float dA = __expf(dt * A[j]);
            h[j] = h[j] * dA + dtx * Bb[j];
            p += h[j] * Cc[j];
        }
        p += __shfl_xor(p, 1, 4);
        p += __shfl_xor(p, 2, 4);
        if (q == 0) {
            size_t r = rowbase + t;
            float sz = zv / (1.f + __expf(-zv));
            y[r * D_INNER + d] = (p + xv * Dd) * sz;
        }

        dt = dt_n; xv = xv_n; Bv = Bv_n; Cv = Cv_n; zv = zv_n;
    }
}

// ---------------------------------------------------------------------------
extern "C" void kernel_launch(void* const* d_in, const int* in_sizes, int n_in,
                              void* d_out, int out_size, void* d_ws, size_t ws_size,
                              hipStream_t stream)
{
    const float* h_in  = (const float*)d_in[0];
    const float* iw    = (const float*)d_in[1];   // (4, 4096, 1024)
    const float* cw    = (const float*)d_in[2];   // (4, 2048, 4)
    const float* cb    = (const float*)d_in[3];   // (4, 2048)
    const float* xw    = (const float*)d_in[4];   // (4, 96, 2048)
    const float* dw    = (const float*)d_in[5];   // (4, 2048, 64)
    const float* db    = (const float*)d_in[6];   // (4, 2048)
    const float* Alog  = (const float*)d_in[7];   // (4, 2048, 16)
    const float* Dp    = (const float*)d_in[8];   // (4, 2048)
    const float* ow    = (const float*)d_in[9];   // (4, 1024, 2048)
    const float* nw    = (const float*)d_in[10];  // (4, 1024)
    const float* nb    = (const float*)d_in[11];  // (4, 1024)
    const float* nfw   = (const float*)d_in[12];  // (1024,)
    const float* nfb   = (const float*)d_in[13];  // (1024,)

    float* ws = (float*)d_ws;
    float* residual = ws;                       // 2,097,152
    float* hs       = residual + 2097152;       // 2,097,152 (LN out; reused as mamba out)
    float* xz       = hs + 2097152;             // 8,388,608
    float* xc       = xz + 8388608;             // 4,194,304
    float* dtb      = xc + 4194304;             // 4,194,304
    float* dbl      = dtb + 4194304;            // 196,608
    float* y        = dbl + 196608;             // 4,194,304

    const float* cur_add = h_in;
    for (int i = 0; i < N_LAYER; ++i) {
        add_ln_kernel<<<NROWS, 256, 0, stream>>>(cur_add, residual,
                                                 nw + i * D_MODEL, nb + i * D_MODEL,
                                                 hs, i == 0);
        // in_proj: (2048 x 1024) * (4096 x 1024)^T -> (2048 x 4096)
        gemm_nt<<<dim3(2 * D_INNER / TILE, NROWS / TILE), 256, 0, stream>>>(
            hs, iw + (size_t)i * 2 * D_INNER * D_MODEL, xz,
            NROWS, 2 * D_INNER, D_MODEL, D_MODEL, D_MODEL, 2 * D_INNER, nullptr, 0);
        // conv + silu
        conv_silu_kernel<<<NB * LSEQ * D_INNER / 256, 256, 0, stream>>>(
            xz, cw + (size_t)i * D_INNER * D_CONV, cb + i * D_INNER, xc);
        // x_proj: (2048 x 2048) * (96 x 2048)^T -> (2048 x 96)
        gemm_nt<<<dim3(2, NROWS / TILE), 256, 0, stream>>>(
            xc, xw + (size_t)i * 96 * D_INNER, dbl,
            NROWS, 96, D_INNER, D_INNER, D_INNER, 96, nullptr, 0);
        // dt_proj + softplus: (2048 x 64 [lda=96]) * (2048 x 64)^T -> (2048 x 2048)
        gemm_nt<<<dim3(D_INNER / TILE, NROWS / TILE), 256, 0, stream>>>(
            dbl, dw + (size_t)i * D_INNER * DT_RANK, dtb,
            NROWS, D_INNER, DT_RANK, 96, DT_RANK, D_INNER, db + i * D_INNER, 1);
        // selective scan (+ D skip + silu(z) gate)
        scan_kernel<<<NB * D_INNER / 16, 64, 0, stream>>>(
            dtb, xc, dbl, xz, Alog + (size_t)i * D_INNER * D_STATE, Dp + i * D_INNER, y);
        // out_proj: (2048 x 2048) * (1024 x 2048)^T -> (2048 x 1024), into hs
        gemm_nt<<<dim3(D_MODEL / TILE, NROWS / TILE), 256, 0, stream>>>(
            y, ow + (size_t)i * D_MODEL * D_INNER, hs,
            NROWS, D_MODEL, D_INNER, D_INNER, D_INNER, D_MODEL, nullptr, 0);
        cur_add = hs;
    }
    add_ln_kernel<<<NROWS, 256, 0, stream>>>(hs, residual, nfw, nfb, (float*)d_out, 0);
}

// Round 3
// 2257.387 us; speedup vs baseline: 2.3226x; 1.6724x over previous
//
#include <hip/hip_runtime.h>
#include <math.h>

#define D_MODEL 1024
#define D_INNER 2048
#define D_STATE 16
#define D_CONV  4
#define DT_RANK 64
#define NB      2
#define LSEQ    1024
#define NROWS   (NB * LSEQ)   // 2048
#define LN_EPS  1e-5f
#define N_LAYER 4

// ---------------------------------------------------------------------------
// Fused residual-add + LayerNorm. One block per row (1024 cols, 256 thr x f4).
// ---------------------------------------------------------------------------
__device__ inline float wave_sum(float s) {
    #pragma unroll
    for (int m = 1; m < 64; m <<= 1) s += __shfl_xor(s, m, 64);
    return s;
}

__global__ __launch_bounds__(256)
void add_ln_kernel(const float* __restrict__ add, float* __restrict__ residual,
                   const float* __restrict__ w, const float* __restrict__ b,
                   float* __restrict__ out, int first)
{
    int row = blockIdx.x;
    int tid = threadIdx.x;
    size_t base = (size_t)row * D_MODEL + tid * 4;

    float4 v = *(const float4*)(add + base);
    if (!first) {
        float4 r = *(const float4*)(residual + base);
        v.x += r.x; v.y += r.y; v.z += r.z; v.w += r.w;
    }
    *(float4*)(residual + base) = v;

    __shared__ float red[8];
    float s = v.x + v.y + v.z + v.w;
    s = wave_sum(s);
    if ((tid & 63) == 0) red[tid >> 6] = s;
    __syncthreads();
    float mu = (red[0] + red[1] + red[2] + red[3]) * (1.0f / D_MODEL);

    float dx = v.x - mu, dy = v.y - mu, dz = v.z - mu, dw2 = v.w - mu;
    float s2 = dx*dx + dy*dy + dz*dz + dw2*dw2;
    s2 = wave_sum(s2);
    if ((tid & 63) == 0) red[4 + (tid >> 6)] = s2;
    __syncthreads();
    float var = (red[4] + red[5] + red[6] + red[7]) * (1.0f / D_MODEL);
    float rs = rsqrtf(var + LN_EPS);

    float4 wv = *(const float4*)(w + tid * 4);
    float4 bv = *(const float4*)(b + tid * 4);
    float4 o;
    o.x = dx  * rs * wv.x + bv.x;
    o.y = dy  * rs * wv.y + bv.y;
    o.z = dz  * rs * wv.z + bv.z;
    o.w = dw2 * rs * wv.w + bv.w;
    *(float4*)(out + base) = o;
}

// ---------------------------------------------------------------------------
// fp32 NT GEMM (small projections: x_proj, dt_proj). 64x64 tile, 4x4/thread.
// mode 1: softplus(acc + bias[n]) epilogue.
// ---------------------------------------------------------------------------
#define TILE 64
#define KT   16

__global__ __launch_bounds__(256)
void gemm_nt(const float* __restrict__ A, const float* __restrict__ B,
             float* __restrict__ C, int M, int N, int K,
             int lda, int ldb, int ldc,
             const float* __restrict__ bias, int mode)
{
    __shared__ float As[KT][TILE + 4];
    __shared__ float Bs[KT][TILE + 4];

    int tid = threadIdx.x;
    int tx = tid & 15, ty = tid >> 4;
    int m0 = blockIdx.y * TILE;
    int n0 = blockIdx.x * TILE;

    int lr = tid >> 2;
    int lk = (tid & 3) * 4;

    float acc[4][4] = {};

    for (int k0 = 0; k0 < K; k0 += KT) {
        {
            int m = m0 + lr;
            float4 v = *(const float4*)(A + (size_t)m * lda + k0 + lk);
            As[lk + 0][lr] = v.x; As[lk + 1][lr] = v.y;
            As[lk + 2][lr] = v.z; As[lk + 3][lr] = v.w;
        }
        {
            int n = n0 + lr;
            float4 v = make_float4(0.f, 0.f, 0.f, 0.f);
            if (n < N) v = *(const float4*)(B + (size_t)n * ldb + k0 + lk);
            Bs[lk + 0][lr] = v.x; Bs[lk + 1][lr] = v.y;
            Bs[lk + 2][lr] = v.z; Bs[lk + 3][lr] = v.w;
        }
        __syncthreads();
        #pragma unroll
        for (int kk = 0; kk < KT; ++kk) {
            float4 a4 = *(const float4*)&As[kk][ty * 4];
            float4 b4 = *(const float4*)&Bs[kk][tx * 4];
            float av[4] = {a4.x, a4.y, a4.z, a4.w};
            float bv[4] = {b4.x, b4.y, b4.z, b4.w};
            #pragma unroll
            for (int i = 0; i < 4; ++i)
                #pragma unroll
                for (int j = 0; j < 4; ++j)
                    acc[i][j] += av[i] * bv[j];
        }
        __syncthreads();
    }

    #pragma unroll
    for (int i = 0; i < 4; ++i) {
        int m = m0 + ty * 4 + i;
        #pragma unroll
        for (int j = 0; j < 4; ++j) {
            int n = n0 + tx * 4 + j;
            if (n >= N) continue;
            float v = acc[i][j];
            if (mode == 1) {
                v += bias[n];
                v = (v > 20.f) ? v : log1pf(__expf(v));
            }
            C[(size_t)m * ldc + n] = v;
        }
    }
}

// ---------------------------------------------------------------------------
// bf16 MFMA NT GEMM: C[M,N] = A[M,K] * B[N,K]^T, fp32 in/out, bf16 convert
// fused into LDS staging. 128x128 tile, BK=64, 4 waves (each 64x64),
// mfma_f32_16x16x32_bf16. Layouts per learn_hip m89/m91 (verified):
//   A/B frag: elem [row = lane&15][k = (lane>>4)*8 + j]
//   C/D:      col = lane&15, row = (lane>>4)*4 + reg
// Requires M%128==0, N%128==0, K%64==0 (true for in_proj / out_proj).
// ---------------------------------------------------------------------------
using bf16x8 = __attribute__((ext_vector_type(8))) short;
using f32x4  = __attribute__((ext_vector_type(4))) float;

#define BBM 128
#define BBN 128
#define BBK 64
#define LDS_S (BBK + 8)   // 72 bf16 -> 144B row stride (16B multiple)

__device__ inline unsigned bfbits(float f) {
    unsigned u = __float_as_uint(f);
    return (u + 0x7fffu + ((u >> 16) & 1u)) >> 16;  // RNE
}

__global__ __launch_bounds__(256)
void gemm_bf16_nt(const float* __restrict__ A, const float* __restrict__ B,
                  float* __restrict__ C, int M, int N, int K)
{
    __shared__ unsigned short As[BBM * LDS_S];
    __shared__ unsigned short Bs[BBN * LDS_S];

    int tid = threadIdx.x;
    int m0 = blockIdx.y * BBM, n0 = blockIdx.x * BBN;
    int lane = tid & 63, w = tid >> 6;
    int wm = (w >> 1) * 64, wn = (w & 1) * 64;
    int lm = lane & 15, q = lane >> 4;

    int lr = tid >> 3;          // 0..31  (staging row)
    int lc = (tid & 7) * 8;     // 0..56  (staging col, bf16 elems)

    f32x4 acc[4][4] = {};

    for (int k0 = 0; k0 < K; k0 += BBK) {
        #pragma unroll
        for (int r = 0; r < 4; ++r) {
            int row = lr + r * 32;
            const float* g = A + (size_t)(m0 + row) * K + k0 + lc;
            float4 v0 = *(const float4*)g;
            float4 v1 = *(const float4*)(g + 4);
            uint4 pv;
            pv.x = (bfbits(v0.y) << 16) | bfbits(v0.x);
            pv.y = (bfbits(v0.w) << 16) | bfbits(v0.z);
            pv.z = (bfbits(v1.y) << 16) | bfbits(v1.x);
            pv.w = (bfbits(v1.w) << 16) | bfbits(v1.z);
            *(uint4*)&As[row * LDS_S + lc] = pv;
        }
        #pragma unroll
        for (int r = 0; r < 4; ++r) {
            int row = lr + r * 32;
            const float* g = B + (size_t)(n0 + row) * K + k0 + lc;
            float4 v0 = *(const float4*)g;
            float4 v1 = *(const float4*)(g + 4);
            uint4 pv;
            pv.x = (bfbits(v0.y) << 16) | bfbits(v0.x);
            pv.y = (bfbits(v0.w) << 16) | bfbits(v0.z);
            pv.z = (bfbits(v1.y) << 16) | bfbits(v1.x);
            pv.w = (bfbits(v1.w) << 16) | bfbits(v1.z);
            *(uint4*)&Bs[row * LDS_S + lc] = pv;
        }
        __syncthreads();
        #pragma unroll
        for (int kk = 0; kk < BBK; kk += 32) {
            bf16x8 af[4], bf[4];
            #pragma unroll
            for (int i = 0; i < 4; ++i)
                af[i] = *(const bf16x8*)&As[(wm + i * 16 + lm) * LDS_S + kk + q * 8];
            #pragma unroll
            for (int j = 0; j < 4; ++j)
                bf[j] = *(const bf16x8*)&Bs[(wn + j * 16 + lm) * LDS_S + kk + q * 8];
            #pragma unroll
            for (int i = 0; i < 4; ++i)
                #pragma unroll
                for (int j = 0; j < 4; ++j)
                    acc[i][j] = __builtin_amdgcn_mfma_f32_16x16x32_bf16(
                        af[i], bf[j], acc[i][j], 0, 0, 0);
        }
        __syncthreads();
    }

    #pragma unroll
    for (int i = 0; i < 4; ++i)
        #pragma unroll
        for (int j = 0; j < 4; ++j)
            #pragma unroll
            for (int r = 0; r < 4; ++r) {
                int row = m0 + wm + i * 16 + q * 4 + r;
                int col = n0 + wn + j * 16 + lm;
                C[(size_t)row * N + col] = acc[i][j][r];
            }
}

// ---------------------------------------------------------------------------
// Depthwise causal conv (width 4) + bias + SiLU.
// ---------------------------------------------------------------------------
__global__ __launch_bounds__(256)
void conv_silu_kernel(const float* __restrict__ xz, const float* __restrict__ cw,
                      const float* __restrict__ cb, float* __restrict__ xc)
{
    int idx = blockIdx.x * 256 + threadIdx.x;
    int d  = idx & (D_INNER - 1);
    int t  = (idx >> 11) & (LSEQ - 1);
    int bb = idx >> 21;

    const float* xcol = xz + (size_t)bb * LSEQ * 2 * D_INNER + d;
    float acc = cb[d];
    #pragma unroll
    for (int k = 0; k < D_CONV; ++k) {
        int tt = t + k - (D_CONV - 1);
        if (tt >= 0) acc += xcol[(size_t)tt * 2 * D_INNER] * cw[d * D_CONV + k];
    }
    acc = acc / (1.f + __expf(-acc));
    xc[idx] = acc;
}

// ---------------------------------------------------------------------------
// Selective scan v3: 4 states/lane, 4 lanes/d, deep software pipeline.
// Ring of SD=4 batches x SU=4 steps (~80 loads in flight) hides the ~900cy
// HBM latency that bounded v2 at ~830 cy/step. Gating + D-skip fused.
// ---------------------------------------------------------------------------
#define SU 4
#define SD 4

__global__ __launch_bounds__(64, 1)
void scan_kernel(const float* __restrict__ dtb, const float* __restrict__ xc,
                 const float* __restrict__ dbl, const float* __restrict__ xz,
                 const float* __restrict__ Alog, const float* __restrict__ Dp,
                 float* __restrict__ y)
{
    int lane = threadIdx.x;
    int q  = lane & 3;
    int dl = lane >> 2;
    int blk = blockIdx.x;
    int bb  = blk >> 7;
    int d   = (blk & 127) * 16 + dl;

    float A[4], h[4] = {0.f, 0.f, 0.f, 0.f};
    #pragma unroll
    for (int j = 0; j < 4; ++j)
        A[j] = -__expf(Alog[d * D_STATE + q * 4 + j]);
    float Dd = Dp[d];
    size_t rowbase = (size_t)bb * LSEQ;

    float  dt_r[SD][SU], xv_r[SD][SU], zv_r[SD][SU];
    float4 B_r[SD][SU], C_r[SD][SU];

    #pragma unroll
    for (int ph = 0; ph < SD; ++ph)
        #pragma unroll
        for (int u = 0; u < SU; ++u) {
            size_t r = rowbase + ph * SU + u;
            dt_r[ph][u] = dtb[r * D_INNER + d];
            xv_r[ph][u] = xc [r * D_INNER + d];
            zv_r[ph][u] = xz [r * 2 * D_INNER + D_INNER + d];
            B_r[ph][u]  = *(const float4*)(dbl + r * 96 + DT_RANK + q * 4);
            C_r[ph][u]  = *(const float4*)(dbl + r * 96 + DT_RANK + D_STATE + q * 4);
        }

    for (int t0 = 0; t0 < LSEQ; t0 += SU * SD) {
        #pragma unroll
        for (int ph = 0; ph < SD; ++ph) {
            #pragma unroll
            for (int u = 0; u < SU; ++u) {
                int t = t0 + ph * SU + u;
                float dt = dt_r[ph][u], xv = xv_r[ph][u], zv = zv_r[ph][u];
                float4 Bv = B_r[ph][u], Cv = C_r[ph][u];
                float dtx = dt * xv;
                float p;
                {
                    float dA;
                    dA = __expf(dt * A[0]); h[0] = h[0] * dA + dtx * Bv.x; p  = h[0] * Cv.x;
                    dA = __expf(dt * A[1]); h[1] = h[1] * dA + dtx * Bv.y; p += h[1] * Cv.y;
                    dA = __expf(dt * A[2]); h[2] = h[2] * dA + dtx * Bv.z; p += h[2] * Cv.z;
                    dA = __expf(dt * A[3]); h[3] = h[3] * dA + dtx * Bv.w; p += h[3] * Cv.w;
                }
                p += __shfl_xor(p, 1, 4);
                p += __shfl_xor(p, 2, 4);
                if (q == 0) {
                    float sz = zv / (1.f + __expf(-zv));
                    y[(rowbase + t) * D_INNER + d] = (p + xv * Dd) * sz;
                }
            }
            size_t tb = (size_t)t0 + (size_t)(ph + SD) * SU;
            #pragma unroll
            for (int u = 0; u < SU; ++u) {
                size_t r = rowbase + ((tb + u) & (LSEQ - 1));
                dt_r[ph][u] = dtb[r * D_INNER + d];
                xv_r[ph][u] = xc [r * D_INNER + d];
                zv_r[ph][u] = xz [r * 2 * D_INNER + D_INNER + d];
                B_r[ph][u]  = *(const float4*)(dbl + r * 96 + DT_RANK + q * 4);
                C_r[ph][u]  = *(const float4*)(dbl + r * 96 + DT_RANK + D_STATE + q * 4);
            }
        }
    }
}

// ---------------------------------------------------------------------------
extern "C" void kernel_launch(void* const* d_in, const int* in_sizes, int n_in,
                              void* d_out, int out_size, void* d_ws, size_t ws_size,
                              hipStream_t stream)
{
    const float* h_in  = (const float*)d_in[0];
    const float* iw    = (const float*)d_in[1];   // (4, 4096, 1024)
    const float* cw    = (const float*)d_in[2];   // (4, 2048, 4)
    const float* cb    = (const float*)d_in[3];   // (4, 2048)
    const float* xw    = (const float*)d_in[4];   // (4, 96, 2048)
    const float* dw    = (const float*)d_in[5];   // (4, 2048, 64)
    const float* db    = (const float*)d_in[6];   // (4, 2048)
    const float* Alog  = (const float*)d_in[7];   // (4, 2048, 16)
    const float* Dp    = (const float*)d_in[8];   // (4, 2048)
    const float* ow    = (const float*)d_in[9];   // (4, 1024, 2048)
    const float* nw    = (const float*)d_in[10];  // (4, 1024)
    const float* nb    = (const float*)d_in[11];  // (4, 1024)
    const float* nfw   = (const float*)d_in[12];  // (1024,)
    const float* nfb   = (const float*)d_in[13];  // (1024,)

    float* ws = (float*)d_ws;
    float* residual = ws;                       // 2,097,152
    float* hs       = residual + 2097152;       // 2,097,152
    float* xz       = hs + 2097152;             // 8,388,608
    float* xc       = xz + 8388608;             // 4,194,304
    float* dtb      = xc + 4194304;             // 4,194,304
    float* dbl      = dtb + 4194304;            // 196,608
    float* y        = dbl + 196608;             // 4,194,304

    const float* cur_add = h_in;
    for (int i = 0; i < N_LAYER; ++i) {
        add_ln_kernel<<<NROWS, 256, 0, stream>>>(cur_add, residual,
                                                 nw + i * D_MODEL, nb + i * D_MODEL,
                                                 hs, i == 0);
        // in_proj (bf16 MFMA): (2048 x 1024) * (4096 x 1024)^T -> (2048 x 4096)
        gemm_bf16_nt<<<dim3(2 * D_INNER / BBN, NROWS / BBM), 256, 0, stream>>>(
            hs, iw + (size_t)i * 2 * D_INNER * D_MODEL, xz,
            NROWS, 2 * D_INNER, D_MODEL);
        // conv + silu
        conv_silu_kernel<<<NB * LSEQ * D_INNER / 256, 256, 0, stream>>>(
            xz, cw + (size_t)i * D_INNER * D_CONV, cb + i * D_INNER, xc);
        // x_proj (fp32): (2048 x 2048) * (96 x 2048)^T -> (2048 x 96)
        gemm_nt<<<dim3(2, NROWS / TILE), 256, 0, stream>>>(
            xc, xw + (size_t)i * 96 * D_INNER, dbl,
            NROWS, 96, D_INNER, D_INNER, D_INNER, 96, nullptr, 0);
        // dt_proj + softplus (fp32): (2048 x 64) * (2048 x 64)^T -> (2048 x 2048)
        gemm_nt<<<dim3(D_INNER / TILE, NROWS / TILE), 256, 0, stream>>>(
            dbl, dw + (size_t)i * D_INNER * DT_RANK, dtb,
            NROWS, D_INNER, DT_RANK, 96, DT_RANK, D_INNER, db + i * D_INNER, 1);
        // selective scan
        scan_kernel<<<NB * D_INNER / 16, 64, 0, stream>>>(
            dtb, xc, dbl, xz, Alog + (size_t)i * D_INNER * D_STATE, Dp + i * D_INNER, y);
        // out_proj (bf16 MFMA): (2048 x 2048) * (1024 x 2048)^T -> (2048 x 1024)
        gemm_bf16_nt<<<dim3(D_MODEL / BBN, NROWS / BBM), 256, 0, stream>>>(
            y, ow + (size_t)i * D_MODEL * D_INNER, hs,
            NROWS, D_MODEL, D_INNER);
        cur_add = hs;
    }
    add_ln_kernel<<<NROWS, 256, 0, stream>>>(hs, residual, nfw, nfb, (float*)d_out, 0);
}

// Round 4
// 1366.800 us; speedup vs baseline: 3.8359x; 1.6516x over previous
//
#include <hip/hip_runtime.h>
#include <math.h>

#define D_MODEL 1024
#define D_INNER 2048
#define D_STATE 16
#define D_CONV  4
#define DT_RANK 64
#define NB      2
#define LSEQ    1024
#define NROWS   (NB * LSEQ)   // 2048
#define LN_EPS  1e-5f
#define N_LAYER 4
#define NCHUNK  16
#define TCH     (LSEQ / NCHUNK)   // 64 steps per chunk

// ---------------------------------------------------------------------------
// Fused residual-add + LayerNorm. One block per row (1024 cols, 256 thr x f4).
// ---------------------------------------------------------------------------
__device__ inline float wave_sum(float s) {
    #pragma unroll
    for (int m = 1; m < 64; m <<= 1) s += __shfl_xor(s, m, 64);
    return s;
}

__global__ __launch_bounds__(256)
void add_ln_kernel(const float* __restrict__ add, float* __restrict__ residual,
                   const float* __restrict__ w, const float* __restrict__ b,
                   float* __restrict__ out, int first)
{
    int row = blockIdx.x;
    int tid = threadIdx.x;
    size_t base = (size_t)row * D_MODEL + tid * 4;

    float4 v = *(const float4*)(add + base);
    if (!first) {
        float4 r = *(const float4*)(residual + base);
        v.x += r.x; v.y += r.y; v.z += r.z; v.w += r.w;
    }
    *(float4*)(residual + base) = v;

    __shared__ float red[8];
    float s = v.x + v.y + v.z + v.w;
    s = wave_sum(s);
    if ((tid & 63) == 0) red[tid >> 6] = s;
    __syncthreads();
    float mu = (red[0] + red[1] + red[2] + red[3]) * (1.0f / D_MODEL);

    float dx = v.x - mu, dy = v.y - mu, dz = v.z - mu, dw2 = v.w - mu;
    float s2 = dx*dx + dy*dy + dz*dz + dw2*dw2;
    s2 = wave_sum(s2);
    if ((tid & 63) == 0) red[4 + (tid >> 6)] = s2;
    __syncthreads();
    float var = (red[4] + red[5] + red[6] + red[7]) * (1.0f / D_MODEL);
    float rs = rsqrtf(var + LN_EPS);

    float4 wv = *(const float4*)(w + tid * 4);
    float4 bv = *(const float4*)(b + tid * 4);
    float4 o;
    o.x = dx  * rs * wv.x + bv.x;
    o.y = dy  * rs * wv.y + bv.y;
    o.z = dz  * rs * wv.z + bv.z;
    o.w = dw2 * rs * wv.w + bv.w;
    *(float4*)(out + base) = o;
}

// ---------------------------------------------------------------------------
// fp32 NT GEMM (dt_proj). 64x64 tile, 4x4/thread. mode 1: softplus(acc+bias).
// ---------------------------------------------------------------------------
#define TILE 64
#define KT   16

__global__ __launch_bounds__(256)
void gemm_nt(const float* __restrict__ A, const float* __restrict__ B,
             float* __restrict__ C, int M, int N, int K,
             int lda, int ldb, int ldc,
             const float* __restrict__ bias, int mode)
{
    __shared__ float As[KT][TILE + 4];
    __shared__ float Bs[KT][TILE + 4];

    int tid = threadIdx.x;
    int tx = tid & 15, ty = tid >> 4;
    int m0 = blockIdx.y * TILE;
    int n0 = blockIdx.x * TILE;

    int lr = tid >> 2;
    int lk = (tid & 3) * 4;

    float acc[4][4] = {};

    for (int k0 = 0; k0 < K; k0 += KT) {
        {
            int m = m0 + lr;
            float4 v = *(const float4*)(A + (size_t)m * lda + k0 + lk);
            As[lk + 0][lr] = v.x; As[lk + 1][lr] = v.y;
            As[lk + 2][lr] = v.z; As[lk + 3][lr] = v.w;
        }
        {
            int n = n0 + lr;
            float4 v = make_float4(0.f, 0.f, 0.f, 0.f);
            if (n < N) v = *(const float4*)(B + (size_t)n * ldb + k0 + lk);
            Bs[lk + 0][lr] = v.x; Bs[lk + 1][lr] = v.y;
            Bs[lk + 2][lr] = v.z; Bs[lk + 3][lr] = v.w;
        }
        __syncthreads();
        #pragma unroll
        for (int kk = 0; kk < KT; ++kk) {
            float4 a4 = *(const float4*)&As[kk][ty * 4];
            float4 b4 = *(const float4*)&Bs[kk][tx * 4];
            float av[4] = {a4.x, a4.y, a4.z, a4.w};
            float bv[4] = {b4.x, b4.y, b4.z, b4.w};
            #pragma unroll
            for (int i = 0; i < 4; ++i)
                #pragma unroll
                for (int j = 0; j < 4; ++j)
                    acc[i][j] += av[i] * bv[j];
        }
        __syncthreads();
    }

    #pragma unroll
    for (int i = 0; i < 4; ++i) {
        int m = m0 + ty * 4 + i;
        #pragma unroll
        for (int j = 0; j < 4; ++j) {
            int n = n0 + tx * 4 + j;
            if (n >= N) continue;
            float v = acc[i][j];
            if (mode == 1) {
                v += bias[n];
                v = (v > 20.f) ? v : log1pf(__expf(v));
            }
            C[(size_t)m * ldc + n] = v;
        }
    }
}

// ---------------------------------------------------------------------------
// fp32 NT GEMM with split-K (x_proj: N=96 -> only 64 blocks otherwise).
// blockIdx.z selects a K-slice; epilogue atomicAdd. C must be pre-zeroed.
// ---------------------------------------------------------------------------
__global__ __launch_bounds__(256)
void gemm_nt_splitk(const float* __restrict__ A, const float* __restrict__ B,
                    float* __restrict__ C, int M, int N, int K,
                    int lda, int ldb, int ldc, int kslice)
{
    __shared__ float As[KT][TILE + 4];
    __shared__ float Bs[KT][TILE + 4];

    int tid = threadIdx.x;
    int tx = tid & 15, ty = tid >> 4;
    int m0 = blockIdx.y * TILE;
    int n0 = blockIdx.x * TILE;
    int kb = blockIdx.z * kslice;

    int lr = tid >> 2;
    int lk = (tid & 3) * 4;

    float acc[4][4] = {};

    for (int k0 = kb; k0 < kb + kslice; k0 += KT) {
        {
            int m = m0 + lr;
            float4 v = *(const float4*)(A + (size_t)m * lda + k0 + lk);
            As[lk + 0][lr] = v.x; As[lk + 1][lr] = v.y;
            As[lk + 2][lr] = v.z; As[lk + 3][lr] = v.w;
        }
        {
            int n = n0 + lr;
            float4 v = make_float4(0.f, 0.f, 0.f, 0.f);
            if (n < N) v = *(const float4*)(B + (size_t)n * ldb + k0 + lk);
            Bs[lk + 0][lr] = v.x; Bs[lk + 1][lr] = v.y;
            Bs[lk + 2][lr] = v.z; Bs[lk + 3][lr] = v.w;
        }
        __syncthreads();
        #pragma unroll
        for (int kk = 0; kk < KT; ++kk) {
            float4 a4 = *(const float4*)&As[kk][ty * 4];
            float4 b4 = *(const float4*)&Bs[kk][tx * 4];
            float av[4] = {a4.x, a4.y, a4.z, a4.w};
            float bv[4] = {b4.x, b4.y, b4.z, b4.w};
            #pragma unroll
            for (int i = 0; i < 4; ++i)
                #pragma unroll
                for (int j = 0; j < 4; ++j)
                    acc[i][j] += av[i] * bv[j];
        }
        __syncthreads();
    }

    #pragma unroll
    for (int i = 0; i < 4; ++i) {
        int m = m0 + ty * 4 + i;
        #pragma unroll
        for (int j = 0; j < 4; ++j) {
            int n = n0 + tx * 4 + j;
            if (n < N) atomicAdd(&C[(size_t)m * ldc + n], acc[i][j]);
        }
    }
}

// ---------------------------------------------------------------------------
// bf16 MFMA NT GEMM (in_proj / out_proj). 128x128 tile, BK=64, 4 waves,
// mfma_f32_16x16x32_bf16; fp32->bf16 fused into LDS staging.
// ---------------------------------------------------------------------------
using bf16x8 = __attribute__((ext_vector_type(8))) short;
using f32x4  = __attribute__((ext_vector_type(4))) float;

#define BBM 128
#define BBN 128
#define BBK 64
#define LDS_S (BBK + 8)

__device__ inline unsigned bfbits(float f) {
    unsigned u = __float_as_uint(f);
    return (u + 0x7fffu + ((u >> 16) & 1u)) >> 16;  // RNE
}

__global__ __launch_bounds__(256)
void gemm_bf16_nt(const float* __restrict__ A, const float* __restrict__ B,
                  float* __restrict__ C, int M, int N, int K)
{
    __shared__ unsigned short As[BBM * LDS_S];
    __shared__ unsigned short Bs[BBN * LDS_S];

    int tid = threadIdx.x;
    int m0 = blockIdx.y * BBM, n0 = blockIdx.x * BBN;
    int lane = tid & 63, w = tid >> 6;
    int wm = (w >> 1) * 64, wn = (w & 1) * 64;
    int lm = lane & 15, q = lane >> 4;

    int lr = tid >> 3;
    int lc = (tid & 7) * 8;

    f32x4 acc[4][4] = {};

    for (int k0 = 0; k0 < K; k0 += BBK) {
        #pragma unroll
        for (int r = 0; r < 4; ++r) {
            int row = lr + r * 32;
            const float* g = A + (size_t)(m0 + row) * K + k0 + lc;
            float4 v0 = *(const float4*)g;
            float4 v1 = *(const float4*)(g + 4);
            uint4 pv;
            pv.x = (bfbits(v0.y) << 16) | bfbits(v0.x);
            pv.y = (bfbits(v0.w) << 16) | bfbits(v0.z);
            pv.z = (bfbits(v1.y) << 16) | bfbits(v1.x);
            pv.w = (bfbits(v1.w) << 16) | bfbits(v1.z);
            *(uint4*)&As[row * LDS_S + lc] = pv;
        }
        #pragma unroll
        for (int r = 0; r < 4; ++r) {
            int row = lr + r * 32;
            const float* g = B + (size_t)(n0 + row) * K + k0 + lc;
            float4 v0 = *(const float4*)g;
            float4 v1 = *(const float4*)(g + 4);
            uint4 pv;
            pv.x = (bfbits(v0.y) << 16) | bfbits(v0.x);
            pv.y = (bfbits(v0.w) << 16) | bfbits(v0.z);
            pv.z = (bfbits(v1.y) << 16) | bfbits(v1.x);
            pv.w = (bfbits(v1.w) << 16) | bfbits(v1.z);
            *(uint4*)&Bs[row * LDS_S + lc] = pv;
        }
        __syncthreads();
        #pragma unroll
        for (int kk = 0; kk < BBK; kk += 32) {
            bf16x8 af[4], bf[4];
            #pragma unroll
            for (int i = 0; i < 4; ++i)
                af[i] = *(const bf16x8*)&As[(wm + i * 16 + lm) * LDS_S + kk + q * 8];
            #pragma unroll
            for (int j = 0; j < 4; ++j)
                bf[j] = *(const bf16x8*)&Bs[(wn + j * 16 + lm) * LDS_S + kk + q * 8];
            #pragma unroll
            for (int i = 0; i < 4; ++i)
                #pragma unroll
                for (int j = 0; j < 4; ++j)
                    acc[i][j] = __builtin_amdgcn_mfma_f32_16x16x32_bf16(
                        af[i], bf[j], acc[i][j], 0, 0, 0);
        }
        __syncthreads();
    }

    #pragma unroll
    for (int i = 0; i < 4; ++i)
        #pragma unroll
        for (int j = 0; j < 4; ++j)
            #pragma unroll
            for (int r = 0; r < 4; ++r) {
                int row = m0 + wm + i * 16 + q * 4 + r;
                int col = n0 + wn + j * 16 + lm;
                C[(size_t)row * N + col] = acc[i][j][r];
            }
}

// ---------------------------------------------------------------------------
// Depthwise causal conv (width 4) + bias + SiLU.
// ---------------------------------------------------------------------------
__global__ __launch_bounds__(256)
void conv_silu_kernel(const float* __restrict__ xz, const float* __restrict__ cw,
                      const float* __restrict__ cb, float* __restrict__ xc)
{
    int idx = blockIdx.x * 256 + threadIdx.x;
    int d  = idx & (D_INNER - 1);
    int t  = (idx >> 11) & (LSEQ - 1);
    int bb = idx >> 21;

    const float* xcol = xz + (size_t)bb * LSEQ * 2 * D_INNER + d;
    float acc = cb[d];
    #pragma unroll
    for (int k = 0; k < D_CONV; ++k) {
        int tt = t + k - (D_CONV - 1);
        if (tt >= 0) acc += xcol[(size_t)tt * 2 * D_INNER] * cw[d * D_CONV + k];
    }
    acc = acc / (1.f + __expf(-acc));
    xc[idx] = acc;
}

// ---------------------------------------------------------------------------
// Chunked selective scan. Recurrence per (d,s): h = a*h + b, a = exp(dt*A),
// b = dt*x*B. Associative compose: (a1,b1)∘(a2,b2) = (a1*a2, a2*b1+b2).
// 16 chunks x 64 steps -> grid 4096 single-wave blocks (~12-16 waves/CU TLP).
// Lane map: q = lane&3 (state quad), dl = lane>>2 (d in group of 16).
// ---------------------------------------------------------------------------
__global__ __launch_bounds__(64)
void scan_pass1(const float* __restrict__ dtb, const float* __restrict__ xc,
                const float* __restrict__ dbl, const float* __restrict__ Alog,
                float* __restrict__ aPbuf, float* __restrict__ bAbuf)
{
    int lane = threadIdx.x;
    int q  = lane & 3;
    int dl = lane >> 2;
    int blk = blockIdx.x;              // ((b*NCHUNK + c)*128 + dg)
    int dg = blk & 127;
    int c  = (blk >> 7) & (NCHUNK - 1);
    int bb = blk >> 11;
    int d  = dg * 16 + dl;

    float A[4];
    #pragma unroll
    for (int j = 0; j < 4; ++j)
        A[j] = -__expf(Alog[d * D_STATE + q * 4 + j]);

    float aP[4] = {1.f, 1.f, 1.f, 1.f};
    float bA[4] = {0.f, 0.f, 0.f, 0.f};
    size_t rowbase = (size_t)bb * LSEQ + (size_t)c * TCH;

    // depth-1 prefetch
    float  dt = dtb[rowbase * D_INNER + d];
    float  xv = xc [rowbase * D_INNER + d];
    float4 Bv = *(const float4*)(dbl + rowbase * 96 + DT_RANK + q * 4);

    for (int t = 0; t < TCH; ++t) {
        int tn = (t + 1 < TCH) ? t + 1 : t;
        size_t rn = rowbase + tn;
        float  dt_n = dtb[rn * D_INNER + d];
        float  xv_n = xc [rn * D_INNER + d];
        float4 Bv_n = *(const float4*)(dbl + rn * 96 + DT_RANK + q * 4);

        float dtx = dt * xv;
        float Bb[4] = {Bv.x, Bv.y, Bv.z, Bv.w};
        #pragma unroll
        for (int j = 0; j < 4; ++j) {
            float a = __expf(dt * A[j]);
            aP[j] *= a;
            bA[j] = bA[j] * a + dtx * Bb[j];
        }
        dt = dt_n; xv = xv_n; Bv = Bv_n;
    }

    size_t o = (((size_t)(bb * NCHUNK + c)) * D_INNER + d) * D_STATE + q * 4;
    *(float4*)(aPbuf + o) = make_float4(aP[0], aP[1], aP[2], aP[3]);
    *(float4*)(bAbuf + o) = make_float4(bA[0], bA[1], bA[2], bA[3]);
}

__global__ __launch_bounds__(64)
void scan_pass2(const float* __restrict__ dtb, const float* __restrict__ xc,
                const float* __restrict__ dbl, const float* __restrict__ xz,
                const float* __restrict__ Alog, const float* __restrict__ Dp,
                const float* __restrict__ aPbuf, const float* __restrict__ bAbuf,
                float* __restrict__ y)
{
    int lane = threadIdx.x;
    int q  = lane & 3;
    int dl = lane >> 2;
    int blk = blockIdx.x;
    int dg = blk & 127;
    int c  = (blk >> 7) & (NCHUNK - 1);
    int bb = blk >> 11;
    int d  = dg * 16 + dl;

    float A[4];
    #pragma unroll
    for (int j = 0; j < 4; ++j)
        A[j] = -__expf(Alog[d * D_STATE + q * 4 + j]);
    float Dd = Dp[d];

    // prefix: compose chunk transfers 0..c-1 (all loads in-bounds; predicated use)
    float h[4] = {0.f, 0.f, 0.f, 0.f};
    {
        float4 aPv[NCHUNK - 1], bAv[NCHUNK - 1];
        #pragma unroll
        for (int cc = 0; cc < NCHUNK - 1; ++cc) {
            size_t o = (((size_t)(bb * NCHUNK + cc)) * D_INNER + d) * D_STATE + q * 4;
            aPv[cc] = *(const float4*)(aPbuf + o);
            bAv[cc] = *(const float4*)(bAbuf + o);
        }
        #pragma unroll
        for (int cc = 0; cc < NCHUNK - 1; ++cc) {
            if (cc < c) {
                h[0] = h[0] * aPv[cc].x + bAv[cc].x;
                h[1] = h[1] * aPv[cc].y + bAv[cc].y;
                h[2] = h[2] * aPv[cc].z + bAv[cc].z;
                h[3] = h[3] * aPv[cc].w + bAv[cc].w;
            }
        }
    }

    size_t rowbase = (size_t)bb * LSEQ + (size_t)c * TCH;

    // depth-1 prefetch replay
    float  dt = dtb[rowbase * D_INNER + d];
    float  xv = xc [rowbase * D_INNER + d];
    float  zv = xz [rowbase * 2 * D_INNER + D_INNER + d];
    float4 Bv = *(const float4*)(dbl + rowbase * 96 + DT_RANK + q * 4);
    float4 Cv = *(const float4*)(dbl + rowbase * 96 + DT_RANK + D_STATE + q * 4);

    for (int t = 0; t < TCH; ++t) {
        int tn = (t + 1 < TCH) ? t + 1 : t;
        size_t rn = rowbase + tn;
        float  dt_n = dtb[rn * D_INNER + d];
        float  xv_n = xc [rn * D_INNER + d];
        float  zv_n = xz [rn * 2 * D_INNER + D_INNER + d];
        float4 Bv_n = *(const float4*)(dbl + rn * 96 + DT_RANK + q * 4);
        float4 Cv_n = *(const float4*)(dbl + rn * 96 + DT_RANK + D_STATE + q * 4);

        float dtx = dt * xv;
        float p;
        {
            float a;
            a = __expf(dt * A[0]); h[0] = h[0] * a + dtx * Bv.x; p  = h[0] * Cv.x;
            a = __expf(dt * A[1]); h[1] = h[1] * a + dtx * Bv.y; p += h[1] * Cv.y;
            a = __expf(dt * A[2]); h[2] = h[2] * a + dtx * Bv.z; p += h[2] * Cv.z;
            a = __expf(dt * A[3]); h[3] = h[3] * a + dtx * Bv.w; p += h[3] * Cv.w;
        }
        p += __shfl_xor(p, 1, 4);
        p += __shfl_xor(p, 2, 4);
        if (q == 0) {
            float sz = zv / (1.f + __expf(-zv));
            y[(rowbase + t) * D_INNER + d] = (p + xv * Dd) * sz;
        }
        dt = dt_n; xv = xv_n; zv = zv_n; Bv = Bv_n; Cv = Cv_n;
    }
}

// ---------------------------------------------------------------------------
extern "C" void kernel_launch(void* const* d_in, const int* in_sizes, int n_in,
                              void* d_out, int out_size, void* d_ws, size_t ws_size,
                              hipStream_t stream)
{
    const float* h_in  = (const float*)d_in[0];
    const float* iw    = (const float*)d_in[1];   // (4, 4096, 1024)
    const float* cw    = (const float*)d_in[2];   // (4, 2048, 4)
    const float* cb    = (const float*)d_in[3];   // (4, 2048)
    const float* xw    = (const float*)d_in[4];   // (4, 96, 2048)
    const float* dw    = (const float*)d_in[5];   // (4, 2048, 64)
    const float* db    = (const float*)d_in[6];   // (4, 2048)
    const float* Alog  = (const float*)d_in[7];   // (4, 2048, 16)
    const float* Dp    = (const float*)d_in[8];   // (4, 2048)
    const float* ow    = (const float*)d_in[9];   // (4, 1024, 2048)
    const float* nw    = (const float*)d_in[10];  // (4, 1024)
    const float* nb    = (const float*)d_in[11];  // (4, 1024)
    const float* nfw   = (const float*)d_in[12];  // (1024,)
    const float* nfb   = (const float*)d_in[13];  // (1024,)

    float* ws = (float*)d_ws;
    float* residual = ws;                       // 2,097,152 floats
    float* hs       = residual + 2097152;       // 2,097,152 (LN out; dead during scan)
    float* xz       = hs + 2097152;             // 8,388,608
    float* xc       = xz + 8388608;             // 4,194,304
    float* dtb      = xc + 4194304;             // 4,194,304
    float* dbl      = dtb + 4194304;            // 196,608
    float* y        = dbl + 196608;             // 4,194,304

    // chunk transfer buffers alias hs (dead between in_proj and out_proj)
    float* aPbuf = hs;                          // 1,048,576 floats
    float* bAbuf = hs + 1048576;                // 1,048,576 floats

    const float* cur_add = h_in;
    for (int i = 0; i < N_LAYER; ++i) {
        add_ln_kernel<<<NROWS, 256, 0, stream>>>(cur_add, residual,
                                                 nw + i * D_MODEL, nb + i * D_MODEL,
                                                 hs, i == 0);
        // in_proj (bf16 MFMA): (2048 x 1024) * (4096 x 1024)^T -> (2048 x 4096)
        gemm_bf16_nt<<<dim3(2 * D_INNER / BBN, NROWS / BBM), 256, 0, stream>>>(
            hs, iw + (size_t)i * 2 * D_INNER * D_MODEL, xz,
            NROWS, 2 * D_INNER, D_MODEL);
        // conv + silu
        conv_silu_kernel<<<NB * LSEQ * D_INNER / 256, 256, 0, stream>>>(
            xz, cw + (size_t)i * D_INNER * D_CONV, cb + i * D_INNER, xc);
        // x_proj (fp32 split-K x8): (2048 x 2048) * (96 x 2048)^T -> (2048 x 96)
        hipMemsetAsync(dbl, 0, 196608 * sizeof(float), stream);
        gemm_nt_splitk<<<dim3(2, NROWS / TILE, 8), 256, 0, stream>>>(
            xc, xw + (size_t)i * 96 * D_INNER, dbl,
            NROWS, 96, D_INNER, D_INNER, D_INNER, 96, D_INNER / 8);
        // dt_proj + softplus (fp32): (2048 x 64) * (2048 x 64)^T -> (2048 x 2048)
        gemm_nt<<<dim3(D_INNER / TILE, NROWS / TILE), 256, 0, stream>>>(
            dbl, dw + (size_t)i * D_INNER * DT_RANK, dtb,
            NROWS, D_INNER, DT_RANK, 96, DT_RANK, D_INNER, db + i * D_INNER, 1);
        // chunked selective scan
        scan_pass1<<<NB * NCHUNK * (D_INNER / 16), 64, 0, stream>>>(
            dtb, xc, dbl, Alog + (size_t)i * D_INNER * D_STATE, aPbuf, bAbuf);
        scan_pass2<<<NB * NCHUNK * (D_INNER / 16), 64, 0, stream>>>(
            dtb, xc, dbl, xz, Alog + (size_t)i * D_INNER * D_STATE, Dp + i * D_INNER,
            aPbuf, bAbuf, y);
        // out_proj (bf16 MFMA): (2048 x 2048) * (1024 x 2048)^T -> (2048 x 1024)
        gemm_bf16_nt<<<dim3(D_MODEL / BBN, NROWS / BBM), 256, 0, stream>>>(
            y, ow + (size_t)i * D_MODEL * D_INNER, hs,
            NROWS, D_MODEL, D_INNER);
        cur_add = hs;
    }
    add_ln_kernel<<<NROWS, 256, 0, stream>>>(hs, residual, nfw, nfb, (float*)d_out, 0);
}

// Round 7
// 1262.755 us; speedup vs baseline: 4.1520x; 1.0824x over previous
//
#include <hip/hip_runtime.h>
#include <math.h>

#define D_MODEL 1024
#define D_INNER 2048
#define D_STATE 16
#define D_CONV  4
#define DT_RANK 64
#define NB      2
#define LSEQ    1024
#define NROWS   (NB * LSEQ)   // 2048
#define LN_EPS  1e-5f
#define N_LAYER 4
#define NCHUNK  16
#define TCH     (LSEQ / NCHUNK)   // 64 steps per chunk

__device__ inline unsigned bfbits(float f) {
    unsigned u = __float_as_uint(f);
    return (u + 0x7fffu + ((u >> 16) & 1u)) >> 16;  // RNE
}

// ---------------------------------------------------------------------------
// Fused residual-add + LayerNorm (r4-proven, fp32 out).
// ---------------------------------------------------------------------------
__device__ inline float wave_sum(float s) {
    #pragma unroll
    for (int m = 1; m < 64; m <<= 1) s += __shfl_xor(s, m, 64);
    return s;
}

__global__ __launch_bounds__(256)
void add_ln_kernel(const float* __restrict__ add, float* __restrict__ residual,
                   const float* __restrict__ w, const float* __restrict__ b,
                   float* __restrict__ out, int first)
{
    int row = blockIdx.x;
    int tid = threadIdx.x;
    size_t base = (size_t)row * D_MODEL + tid * 4;

    float4 v = *(const float4*)(add + base);
    if (!first) {
        float4 r = *(const float4*)(residual + base);
        v.x += r.x; v.y += r.y; v.z += r.z; v.w += r.w;
    }
    *(float4*)(residual + base) = v;

    __shared__ float red[8];
    float s = v.x + v.y + v.z + v.w;
    s = wave_sum(s);
    if ((tid & 63) == 0) red[tid >> 6] = s;
    __syncthreads();
    float mu = (red[0] + red[1] + red[2] + red[3]) * (1.0f / D_MODEL);

    float dx = v.x - mu, dy = v.y - mu, dz = v.z - mu, dw2 = v.w - mu;
    float s2 = dx*dx + dy*dy + dz*dz + dw2*dw2;
    s2 = wave_sum(s2);
    if ((tid & 63) == 0) red[4 + (tid >> 6)] = s2;
    __syncthreads();
    float var = (red[4] + red[5] + red[6] + red[7]) * (1.0f / D_MODEL);
    float rs = rsqrtf(var + LN_EPS);

    float4 wv = *(const float4*)(w + tid * 4);
    float4 bv = *(const float4*)(b + tid * 4);
    float4 o;
    o.x = dx  * rs * wv.x + bv.x;
    o.y = dy  * rs * wv.y + bv.y;
    o.z = dz  * rs * wv.z + bv.z;
    o.w = dw2 * rs * wv.w + bv.w;
    *(float4*)(out + base) = o;
}

// ---------------------------------------------------------------------------
// fp32 -> bf16 bulk convert (weights). grid*256*4 must equal element count.
// ---------------------------------------------------------------------------
__global__ __launch_bounds__(256)
void f32_to_bf16_kernel(const float* __restrict__ src, unsigned short* __restrict__ dst)
{
    int i = blockIdx.x * 256 + threadIdx.x;
    float4 v = *(const float4*)(src + (size_t)i * 4);
    ushort4 o;
    o.x = (unsigned short)bfbits(v.x);
    o.y = (unsigned short)bfbits(v.y);
    o.z = (unsigned short)bfbits(v.z);
    o.w = (unsigned short)bfbits(v.w);
    *(ushort4*)(dst + (size_t)i * 4) = o;
}

// ---------------------------------------------------------------------------
// fp32 NT GEMM (dt_proj). 64x64 tile, 4x4/thread. mode 1: softplus(acc+bias).
// ---------------------------------------------------------------------------
#define TILE 64
#define KT   16

__global__ __launch_bounds__(256)
void gemm_nt(const float* __restrict__ A, const float* __restrict__ B,
             float* __restrict__ C, int M, int N, int K,
             int lda, int ldb, int ldc,
             const float* __restrict__ bias, int mode)
{
    __shared__ float As[KT][TILE + 4];
    __shared__ float Bs[KT][TILE + 4];

    int tid = threadIdx.x;
    int tx = tid & 15, ty = tid >> 4;
    int m0 = blockIdx.y * TILE;
    int n0 = blockIdx.x * TILE;

    int lr = tid >> 2;
    int lk = (tid & 3) * 4;

    float acc[4][4] = {};

    for (int k0 = 0; k0 < K; k0 += KT) {
        {
            int m = m0 + lr;
            float4 v = *(const float4*)(A + (size_t)m * lda + k0 + lk);
            As[lk + 0][lr] = v.x; As[lk + 1][lr] = v.y;
            As[lk + 2][lr] = v.z; As[lk + 3][lr] = v.w;
        }
        {
            int n = n0 + lr;
            float4 v = make_float4(0.f, 0.f, 0.f, 0.f);
            if (n < N) v = *(const float4*)(B + (size_t)n * ldb + k0 + lk);
            Bs[lk + 0][lr] = v.x; Bs[lk + 1][lr] = v.y;
            Bs[lk + 2][lr] = v.z; Bs[lk + 3][lr] = v.w;
        }
        __syncthreads();
        #pragma unroll
        for (int kk = 0; kk < KT; ++kk) {
            float4 a4 = *(const float4*)&As[kk][ty * 4];
            float4 b4 = *(const float4*)&Bs[kk][tx * 4];
            float av[4] = {a4.x, a4.y, a4.z, a4.w};
            float bv[4] = {b4.x, b4.y, b4.z, b4.w};
            #pragma unroll
            for (int i = 0; i < 4; ++i)
                #pragma unroll
                for (int j = 0; j < 4; ++j)
                    acc[i][j] += av[i] * bv[j];
        }
        __syncthreads();
    }

    #pragma unroll
    for (int i = 0; i < 4; ++i) {
        int m = m0 + ty * 4 + i;
        #pragma unroll
        for (int j = 0; j < 4; ++j) {
            int n = n0 + tx * 4 + j;
            if (n >= N) continue;
            float v = acc[i][j];
            if (mode == 1) {
                v += bias[n];
                v = (v > 20.f) ? v : log1pf(__expf(v));
            }
            C[(size_t)m * ldc + n] = v;
        }
    }
}

// ---------------------------------------------------------------------------
// fp32 NT GEMM with split-K (x_proj). C pre-zeroed; atomicAdd epilogue.
// ---------------------------------------------------------------------------
__global__ __launch_bounds__(256)
void gemm_nt_splitk(const float* __restrict__ A, const float* __restrict__ B,
                    float* __restrict__ C, int M, int N, int K,
                    int lda, int ldb, int ldc, int kslice)
{
    __shared__ float As[KT][TILE + 4];
    __shared__ float Bs[KT][TILE + 4];

    int tid = threadIdx.x;
    int tx = tid & 15, ty = tid >> 4;
    int m0 = blockIdx.y * TILE;
    int n0 = blockIdx.x * TILE;
    int kb = blockIdx.z * kslice;

    int lr = tid >> 2;
    int lk = (tid & 3) * 4;

    float acc[4][4] = {};

    for (int k0 = kb; k0 < kb + kslice; k0 += KT) {
        {
            int m = m0 + lr;
            float4 v = *(const float4*)(A + (size_t)m * lda + k0 + lk);
            As[lk + 0][lr] = v.x; As[lk + 1][lr] = v.y;
            As[lk + 2][lr] = v.z; As[lk + 3][lr] = v.w;
        }
        {
            int n = n0 + lr;
            float4 v = make_float4(0.f, 0.f, 0.f, 0.f);
            if (n < N) v = *(const float4*)(B + (size_t)n * ldb + k0 + lk);
            Bs[lk + 0][lr] = v.x; Bs[lk + 1][lr] = v.y;
            Bs[lk + 2][lr] = v.z; Bs[lk + 3][lr] = v.w;
        }
        __syncthreads();
        #pragma unroll
        for (int kk = 0; kk < KT; ++kk) {
            float4 a4 = *(const float4*)&As[kk][ty * 4];
            float4 b4 = *(const float4*)&Bs[kk][tx * 4];
            float av[4] = {a4.x, a4.y, a4.z, a4.w};
            float bv[4] = {b4.x, b4.y, b4.z, b4.w};
            #pragma unroll
            for (int i = 0; i < 4; ++i)
                #pragma unroll
                for (int j = 0; j < 4; ++j)
                    acc[i][j] += av[i] * bv[j];
        }
        __syncthreads();
    }

    #pragma unroll
    for (int i = 0; i < 4; ++i) {
        int m = m0 + ty * 4 + i;
        #pragma unroll
        for (int j = 0; j < 4; ++j) {
            int n = n0 + tx * 4 + j;
            if (n < N) atomicAdd(&C[(size_t)m * ldc + n], acc[i][j]);
        }
    }
}

// ---------------------------------------------------------------------------
// bf16 MFMA NT GEMM — r4-proven kernel, ONE change: B operand arrives
// pre-converted as bf16 (uint4 passthrough staging). A stays fp32 with
// in-kernel conversion (bit-identical to r4). 128x128 tile, BK=64, 4 waves,
// mfma_f32_16x16x32_bf16, LDS_S=72 padded layout (r4-proven).
// ---------------------------------------------------------------------------
using bf16x8 = __attribute__((ext_vector_type(8))) short;
using f32x4  = __attribute__((ext_vector_type(4))) float;

#define BBM 128
#define BBN 128
#define BBK 64
#define LDS_S (BBK + 8)   // 72 bf16 -> 144B row stride

__global__ __launch_bounds__(256)
void gemm_bf16_nt(const float* __restrict__ A, const unsigned short* __restrict__ Bw,
                  float* __restrict__ C, int M, int N, int K)
{
    __shared__ unsigned short As[BBM * LDS_S];
    __shared__ unsigned short Bs[BBN * LDS_S];

    int tid = threadIdx.x;
    int m0 = blockIdx.y * BBM, n0 = blockIdx.x * BBN;
    int lane = tid & 63, w = tid >> 6;
    int wm = (w >> 1) * 64, wn = (w & 1) * 64;
    int lm = lane & 15, q = lane >> 4;

    int lr = tid >> 3;          // 0..31  (staging row)
    int lc = (tid & 7) * 8;     // 0..56  (staging col, bf16 elems)

    f32x4 acc[4][4] = {};

    for (int k0 = 0; k0 < K; k0 += BBK) {
        #pragma unroll
        for (int r = 0; r < 4; ++r) {
            int row = lr + r * 32;
            const float* g = A + (size_t)(m0 + row) * K + k0 + lc;
            float4 v0 = *(const float4*)g;
            float4 v1 = *(const float4*)(g + 4);
            uint4 pv;
            pv.x = (bfbits(v0.y) << 16) | bfbits(v0.x);
            pv.y = (bfbits(v0.w) << 16) | bfbits(v0.z);
            pv.z = (bfbits(v1.y) << 16) | bfbits(v1.x);
            pv.w = (bfbits(v1.w) << 16) | bfbits(v1.z);
            *(uint4*)&As[row * LDS_S + lc] = pv;
        }
        #pragma unroll
        for (int r = 0; r < 4; ++r) {
            int row = lr + r * 32;
            uint4 pv = *(const uint4*)(Bw + (size_t)(n0 + row) * K + k0 + lc);
            *(uint4*)&Bs[row * LDS_S + lc] = pv;
        }
        __syncthreads();
        #pragma unroll
        for (int kk = 0; kk < BBK; kk += 32) {
            bf16x8 af[4], bf[4];
            #pragma unroll
            for (int i = 0; i < 4; ++i)
                af[i] = *(const bf16x8*)&As[(wm + i * 16 + lm) * LDS_S + kk + q * 8];
            #pragma unroll
            for (int j = 0; j < 4; ++j)
                bf[j] = *(const bf16x8*)&Bs[(wn + j * 16 + lm) * LDS_S + kk + q * 8];
            #pragma unroll
            for (int i = 0; i < 4; ++i)
                #pragma unroll
                for (int j = 0; j < 4; ++j)
                    acc[i][j] = __builtin_amdgcn_mfma_f32_16x16x32_bf16(
                        af[i], bf[j], acc[i][j], 0, 0, 0);
        }
        __syncthreads();
    }

    #pragma unroll
    for (int i = 0; i < 4; ++i)
        #pragma unroll
        for (int j = 0; j < 4; ++j)
            #pragma unroll
            for (int r = 0; r < 4; ++r) {
                int row = m0 + wm + i * 16 + q * 4 + r;
                int col = n0 + wn + j * 16 + lm;
                C[(size_t)row * N + col] = acc[i][j][r];
            }
}

// ---------------------------------------------------------------------------
// Depthwise causal conv (width 4) + bias + SiLU.
// ---------------------------------------------------------------------------
__global__ __launch_bounds__(256)
void conv_silu_kernel(const float* __restrict__ xz, const float* __restrict__ cw,
                      const float* __restrict__ cb, float* __restrict__ xc)
{
    int idx = blockIdx.x * 256 + threadIdx.x;
    int d  = idx & (D_INNER - 1);
    int t  = (idx >> 11) & (LSEQ - 1);
    int bb = idx >> 21;

    const float* xcol = xz + (size_t)bb * LSEQ * 2 * D_INNER + d;
    float acc = cb[d];
    #pragma unroll
    for (int k = 0; k < D_CONV; ++k) {
        int tt = t + k - (D_CONV - 1);
        if (tt >= 0) acc += xcol[(size_t)tt * 2 * D_INNER] * cw[d * D_CONV + k];
    }
    acc = acc / (1.f + __expf(-acc));
    xc[idx] = acc;
}

// ---------------------------------------------------------------------------
// Chunked selective scan (r4-proven). pass1: chunk transfer ops; pass2:
// prefix compose + replay with fused D-skip and silu(z) gate (fp32 y out).
// ---------------------------------------------------------------------------
__global__ __launch_bounds__(64)
void scan_pass1(const float* __restrict__ dtb, const float* __restrict__ xc,
                const float* __restrict__ dbl, const float* __restrict__ Alog,
                float* __restrict__ aPbuf, float* __restrict__ bAbuf)
{
    int lane = threadIdx.x;
    int q  = lane & 3;
    int dl = lane >> 2;
    int blk = blockIdx.x;
    int dg = blk & 127;
    int c  = (blk >> 7) & (NCHUNK - 1);
    int bb = blk >> 11;
    int d  = dg * 16 + dl;

    float A[4];
    #pragma unroll
    for (int j = 0; j < 4; ++j)
        A[j] = -__expf(Alog[d * D_STATE + q * 4 + j]);

    float aP[4] = {1.f, 1.f, 1.f, 1.f};
    float bA[4] = {0.f, 0.f, 0.f, 0.f};
    size_t rowbase = (size_t)bb * LSEQ + (size_t)c * TCH;

    float  dt = dtb[rowbase * D_INNER + d];
    float  xv = xc [rowbase * D_INNER + d];
    float4 Bv = *(const float4*)(dbl + rowbase * 96 + DT_RANK + q * 4);

    for (int t = 0; t < TCH; ++t) {
        int tn = (t + 1 < TCH) ? t + 1 : t;
        size_t rn = rowbase + tn;
        float  dt_n = dtb[rn * D_INNER + d];
        float  xv_n = xc [rn * D_INNER + d];
        float4 Bv_n = *(const float4*)(dbl + rn * 96 + DT_RANK + q * 4);

        float dtx = dt * xv;
        float Bb[4] = {Bv.x, Bv.y, Bv.z, Bv.w};
        #pragma unroll
        for (int j = 0; j < 4; ++j) {
            float a = __expf(dt * A[j]);
            aP[j] *= a;
            bA[j] = bA[j] * a + dtx * Bb[j];
        }
        dt = dt_n; xv = xv_n; Bv = Bv_n;
    }

    size_t o = (((size_t)(bb * NCHUNK + c)) * D_INNER + d) * D_STATE + q * 4;
    *(float4*)(aPbuf + o) = make_float4(aP[0], aP[1], aP[2], aP[3]);
    *(float4*)(bAbuf + o) = make_float4(bA[0], bA[1], bA[2], bA[3]);
}

__global__ __launch_bounds__(64)
void scan_pass2(const float* __restrict__ dtb, const float* __restrict__ xc,
                const float* __restrict__ dbl, const float* __restrict__ xz,
                const float* __restrict__ Alog, const float* __restrict__ Dp,
                const float* __restrict__ aPbuf, const float* __restrict__ bAbuf,
                float* __restrict__ y)
{
    int lane = threadIdx.x;
    int q  = lane & 3;
    int dl = lane >> 2;
    int blk = blockIdx.x;
    int dg = blk & 127;
    int c  = (blk >> 7) & (NCHUNK - 1);
    int bb = blk >> 11;
    int d  = dg * 16 + dl;

    float A[4];
    #pragma unroll
    for (int j = 0; j < 4; ++j)
        A[j] = -__expf(Alog[d * D_STATE + q * 4 + j]);
    float Dd = Dp[d];

    float h[4] = {0.f, 0.f, 0.f, 0.f};
    {
        float4 aPv[NCHUNK - 1], bAv[NCHUNK - 1];
        #pragma unroll
        for (int cc = 0; cc < NCHUNK - 1; ++cc) {
            size_t o = (((size_t)(bb * NCHUNK + cc)) * D_INNER + d) * D_STATE + q * 4;
            aPv[cc] = *(const float4*)(aPbuf + o);
            bAv[cc] = *(const float4*)(bAbuf + o);
        }
        #pragma unroll
        for (int cc = 0; cc < NCHUNK - 1; ++cc) {
            if (cc < c) {
                h[0] = h[0] * aPv[cc].x + bAv[cc].x;
                h[1] = h[1] * aPv[cc].y + bAv[cc].y;
                h[2] = h[2] * aPv[cc].z + bAv[cc].z;
                h[3] = h[3] * aPv[cc].w + bAv[cc].w;
            }
        }
    }

    size_t rowbase = (size_t)bb * LSEQ + (size_t)c * TCH;

    float  dt = dtb[rowbase * D_INNER + d];
    float  xv = xc [rowbase * D_INNER + d];
    float  zv = xz [rowbase * 2 * D_INNER + D_INNER + d];
    float4 Bv = *(const float4*)(dbl + rowbase * 96 + DT_RANK + q * 4);
    float4 Cv = *(const float4*)(dbl + rowbase * 96 + DT_RANK + D_STATE + q * 4);

    for (int t = 0; t < TCH; ++t) {
        int tn = (t + 1 < TCH) ? t + 1 : t;
        size_t rn = rowbase + tn;
        float  dt_n = dtb[rn * D_INNER + d];
        float  xv_n = xc [rn * D_INNER + d];
        float  zv_n = xz [rn * 2 * D_INNER + D_INNER + d];
        float4 Bv_n = *(const float4*)(dbl + rn * 96 + DT_RANK + q * 4);
        float4 Cv_n = *(const float4*)(dbl + rn * 96 + DT_RANK + D_STATE + q * 4);

        float dtx = dt * xv;
        float p;
        {
            float a;
            a = __expf(dt * A[0]); h[0] = h[0] * a + dtx * Bv.x; p  = h[0] * Cv.x;
            a = __expf(dt * A[1]); h[1] = h[1] * a + dtx * Bv.y; p += h[1] * Cv.y;
            a = __expf(dt * A[2]); h[2] = h[2] * a + dtx * Bv.z; p += h[2] * Cv.z;
            a = __expf(dt * A[3]); h[3] = h[3] * a + dtx * Bv.w; p += h[3] * Cv.w;
        }
        p += __shfl_xor(p, 1, 4);
        p += __shfl_xor(p, 2, 4);
        if (q == 0) {
            float sz = zv / (1.f + __expf(-zv));
            y[(rowbase + t) * D_INNER + d] = (p + xv * Dd) * sz;
        }
        dt = dt_n; xv = xv_n; zv = zv_n; Bv = Bv_n; Cv = Cv_n;
    }
}

// ---------------------------------------------------------------------------
extern "C" void kernel_launch(void* const* d_in, const int* in_sizes, int n_in,
                              void* d_out, int out_size, void* d_ws, size_t ws_size,
                              hipStream_t stream)
{
    const float* h_in  = (const float*)d_in[0];
    const float* iw    = (const float*)d_in[1];   // (4, 4096, 1024)
    const float* cw    = (const float*)d_in[2];   // (4, 2048, 4)
    const float* cb    = (const float*)d_in[3];   // (4, 2048)
    const float* xw    = (const float*)d_in[4];   // (4, 96, 2048)
    const float* dw    = (const float*)d_in[5];   // (4, 2048, 64)
    const float* db    = (const float*)d_in[6];   // (4, 2048)
    const float* Alog  = (const float*)d_in[7];   // (4, 2048, 16)
    const float* Dp    = (const float*)d_in[8];   // (4, 2048)
    const float* ow    = (const float*)d_in[9];   // (4, 1024, 2048)
    const float* nw    = (const float*)d_in[10];  // (4, 1024)
    const float* nb    = (const float*)d_in[11];  // (4, 1024)
    const float* nfw   = (const float*)d_in[12];  // (1024,)
    const float* nfb   = (const float*)d_in[13];  // (1024,)

    // workspace layout — EXACTLY round 4's (passed): 25,362,432 floats
    float* ws = (float*)d_ws;
    float* residual = ws;                       // 2,097,152
    float* hs       = residual + 2097152;       // 2,097,152 (LN out; dead during scan)
    float* xz       = hs + 2097152;             // 8,388,608
    float* xc       = xz + 8388608;             // 4,194,304
    float* dtb      = xc + 4194304;             // 4,194,304
    float* dbl      = dtb + 4194304;            // 196,608
    float* y        = dbl + 196608;             // 4,194,304

    // chunk transfer buffers alias hs (dead between add_ln and out_proj) — r4-proven
    float* aPbuf = hs;
    float* bAbuf = hs + 1048576;

    // bf16 weight staging in dead regions (no new workspace):
    //  - in_proj weights (4096x1024 bf16 = 2,097,152 floats) live in y[0..2M)
    //    (y is dead until scan_pass2; in_proj consumes wbuf before that)
    //  - out_proj weights (1024x2048 bf16 = 1,048,576 floats) live in dtb[0..1M)
    //    (dtb is dead after scan_pass2 reads it; converted after scan_pass2)
    unsigned short* wbuf_in  = (unsigned short*)y;
    unsigned short* wbuf_out = (unsigned short*)dtb;

    const float* cur_add = h_in;
    for (int i = 0; i < N_LAYER; ++i) {
        add_ln_kernel<<<NROWS, 256, 0, stream>>>(cur_add, residual,
                                                 nw + i * D_MODEL, nb + i * D_MODEL,
                                                 hs, i == 0);
        // convert in_proj weights: 4096x1024 fp32 -> bf16 (into dead y space)
        f32_to_bf16_kernel<<<(2 * D_INNER * D_MODEL) / 1024, 256, 0, stream>>>(
            iw + (size_t)i * 2 * D_INNER * D_MODEL, wbuf_in);
        // in_proj (bf16 MFMA): (2048 x 1024) * (4096 x 1024)^T -> (2048 x 4096)
        gemm_bf16_nt<<<dim3(2 * D_INNER / BBN, NROWS / BBM), 256, 0, stream>>>(
            hs, wbuf_in, xz, NROWS, 2 * D_INNER, D_MODEL);
        // conv + silu
        conv_silu_kernel<<<NB * LSEQ * D_INNER / 256, 256, 0, stream>>>(
            xz, cw + (size_t)i * D_INNER * D_CONV, cb + i * D_INNER, xc);
        // x_proj (fp32 split-K x8): (2048 x 2048) * (96 x 2048)^T -> (2048 x 96)
        hipMemsetAsync(dbl, 0, 196608 * sizeof(float), stream);
        gemm_nt_splitk<<<dim3(2, NROWS / TILE, 8), 256, 0, stream>>>(
            xc, xw + (size_t)i * 96 * D_INNER, dbl,
            NROWS, 96, D_INNER, D_INNER, D_INNER, 96, D_INNER / 8);
        // dt_proj + softplus (fp32): (2048 x 64) * (2048 x 64)^T -> (2048 x 2048)
        gemm_nt<<<dim3(D_INNER / TILE, NROWS / TILE), 256, 0, stream>>>(
            dbl, dw + (size_t)i * D_INNER * DT_RANK, dtb,
            NROWS, D_INNER, DT_RANK, 96, DT_RANK, D_INNER, db + i * D_INNER, 1);
        // chunked selective scan (pass2 overwrites wbuf_in region with y — ok)
        scan_pass1<<<NB * NCHUNK * (D_INNER / 16), 64, 0, stream>>>(
            dtb, xc, dbl, Alog + (size_t)i * D_INNER * D_STATE, aPbuf, bAbuf);
        scan_pass2<<<NB * NCHUNK * (D_INNER / 16), 64, 0, stream>>>(
            dtb, xc, dbl, xz, Alog + (size_t)i * D_INNER * D_STATE, Dp + i * D_INNER,
            aPbuf, bAbuf, y);
        // convert out_proj weights: 1024x2048 fp32 -> bf16 (into dead dtb space)
        f32_to_bf16_kernel<<<(D_MODEL * D_INNER) / 1024, 256, 0, stream>>>(
            ow + (size_t)i * D_MODEL * D_INNER, wbuf_out);
        // out_proj (bf16 MFMA): (2048 x 2048) * (1024 x 2048)^T -> (2048 x 1024)
        gemm_bf16_nt<<<dim3(D_MODEL / BBN, NROWS / BBM), 256, 0, stream>>>(
            y, wbuf_out, hs, NROWS, D_MODEL, D_INNER);
        cur_add = hs;
    }
    add_ln_kernel<<<NROWS, 256, 0, stream>>>(hs, residual, nfw, nfb, (float*)d_out, 0);
}